// Round 4
// baseline (128.183 us; speedup 1.0000x reference)
//
#include <hip/hip_runtime.h>

// EvalEig round 11: MEASUREMENT ROUND (pre-committed in r9). Four consecutive
// nulls (store coalescing r7, occupancy/serial-depth r8, b128 table reads r10,
// spill round-trip r9/r10) on a kernel modeled at 10-15us but attributed
// ~38us. The attribution "solve = dur - fill - final" was never verified:
// solve never appears in rocprof top-5 (all poison fills, 43-49us), so all
// we know is solve < 43us. This round: solve_kernel byte-identical to r10;
// kernel_launch launches it THREE times (idempotent: reads only energy,
// rewrites identical out/ws). solve = (dur_r11 - dur_r10)/2, normalized by
// fill-row machine drift. Pre-committed worlds: ~162us total -> solve=38,
// model wrong, profile solve directly; ~116-126 -> fixed overhead dominates,
// pivot to launch structure; ~250 -> dur excludes fills, rethink entirely.

namespace {
constexpr int kNE    = 4096;
constexpr int kNCH   = kNE * 3;        // 12288 chains
constexpr int kMatch = 100;
constexpr float kC   = 3.0f / 40.0f * 0.01f;
constexpr float kK1  = 13.0f / 15.0f * 0.01f;
constexpr float kK2  = 7.0f / 60.0f * 0.01f;
constexpr int kSeg        = 32;           // segments per chain
constexpr int kCPB        = 16;           // chains per block
constexpr int kZeroBlocks = kNCH / 512;   // 24
constexpr int kInfBlocks  = kNCH / kCPB;  // 768
}

__device__ __forceinline__ float rcp_f(float x) { return __builtin_amdgcn_rcpf(x); }
__device__ __forceinline__ float rcp_nr(float x) {
    float r = __builtin_amdgcn_rcpf(x);
    return fmaf(fmaf(-x, r, 1.0f), r, r);
}

__global__ __launch_bounds__(512, 4) void solve_kernel(const float* __restrict__ energy,
                                                       float* __restrict__ out,
                                                       float* __restrict__ ws)
{
    // gtp[k] = 1/(100 - 0.1*(k-3)) for k in [4,901] (j = k-3 in [1,898]);
    // dummies = 1.0 elsewhere. +3 shift makes every group read 16B-aligned
    // (jstart === 1 mod 4  ->  padded base jstart+3 === 0 mod 4).
    __shared__ __align__(16) float gtp[908];  // 3.6 KB
    __shared__ float sM[kSeg][4][kCPB][4];    // 32 KB: [seg][matrix row][chain][col]
    float* sF = &sM[0][0][0][0];

    const int bid = (int)blockIdx.x;
    const int tid = (int)threadIdx.x;
    float* uzero = out + kNCH;
    float* uinf  = out + kNCH + (size_t)kMatch * kNCH;

    if (bid < kZeroBlocks) {
        // ---------------- u_zero: outward solve, 94 steps, 1 thread/chain ----
        const int t  = bid * 512 + tid;
        const int l  = t % 3;
        const int ei = t / 3;
        const float e = energy[ei], negE = -e;
        const float ll1 = (float)(l * (l + 1));
        const float rdiv = (l == 0) ? 0.5f : ((l == 1) ? 0.25f : (1.0f/6.0f));
        float p0,p1,p2,p3,p4;
        {
            float pw[5];
            #pragma unroll
            for (int k = 0; k < 5; ++k) {
                float r = 0.1f * (float)(k + 1);
                float rl1 = (l == 0) ? r : ((l == 1) ? r*r : r*r*r);
                pw[k] = rl1 - (rl1 * r) * rdiv;
                uzero[(size_t)k * kNCH + t] = pw[k];
            }
            uzero[(size_t)5 * kNCH + t] = pw[4];
            p0=pw[0]; p1=pw[1]; p2=pw[2]; p3=pw[3]; p4=pw[4];
        }
        float acc4, acc2;
        {
            float q0=p0*p0, q1=p1*p1, q2=p2*p2, q3=p3*p3, q4=p4*p4;
            acc4 = 7.0f*q0*q0 + 32.0f*q1*q1 + 32.0f*q3*q3 + 14.0f*q4*q4 + 32.0f*q4*q4;
            acc2 = q2;
        }
        float f0, f1, f2, f3;
        {
            float i1 = rcp_f(0.2f), i2 = rcp_f(0.3f), i3 = rcp_f(0.4f), i4 = rcp_f(0.5f);
            f0 = fmaf(i1, fmaf(ll1, i1, -1.0f), negE);
            f1 = fmaf(i2, fmaf(ll1, i2, -1.0f), negE);
            f2 = fmaf(i3, fmaf(ll1, i3, -1.0f), negE);
            f3 = fmaf(i4, fmaf(ll1, i4, -1.0f), negE);
        }
        float* ptr = uzero + (size_t)6 * kNCH + t;
        #pragma unroll 4
        for (int j = 5; j <= 98; ++j) {
            float ri = rcp_f(fmaf((float)j, 0.1f, 0.1f));
            float f4 = fmaf(ri, fmaf(ll1, ri, -1.0f), negE);
            float iv = rcp_f(fmaf(-kC, f4, 1.0f));
            float a  = fmaf(kC  * f0, iv, -1.0f);
            float b  = fmaf(kK1 * f1, iv,  2.0f);
            float cc = fmaf(kK2 * f2, iv, -2.0f);
            float d  = fmaf(kK1 * f3, iv,  2.0f);
            float nw = fmaf(d, p4, fmaf(cc, p3, fmaf(b, p2, a * p1)));
            *ptr = nw; ptr += kNCH;
            float v2 = nw*nw, v4 = v2*v2;
            if (j <= 94) {
                int m = (j + 1) & 3;
                if (m == 2)      acc2 += v2;
                else if (m == 0) acc4 += 14.0f * v4;
                else             acc4 += 32.0f * v4;
            } else if (j == 95) {
                acc4 += 7.0f * v4;
            }
            f0 = f1; f1 = f2; f2 = f3; f3 = f4;
            p0 = p1; p1 = p2; p2 = p3; p3 = p4; p4 = nw;
        }
        float integ = fmaf(12.0f, acc2, acc4) * (2.0f * 0.1f / 45.0f);
        float deriv = fmaf(25.0f, p4, fmaf(-48.0f, p3, fmaf(36.0f, p2,
                      fmaf(-16.0f, p1, 3.0f * p0)))) * (1.0f / 1.2f);
        ws[2 * kNCH + t] = deriv / p4;
        ws[3 * kNCH + t] = integ / (p4 * p4);
        return;
    }

    // ---------------- u_infty: 32-segment inward solve ----------------
    for (int k = tid; k < 908; k += 512) {
        int j = k - 3;
        gtp[k] = (j >= 1 && j <= 898) ? rcp_nr(fmaf((float)j, -0.1f, 100.0f)) : 1.0f;
    }
    __syncthreads();

    const int b = bid - kZeroBlocks;
    const int g = tid & (kCPB - 1);        // chain within block
    const int s = tid >> 4;                // segment 0..31 (4 per wave)
    const int t = b * kCPB + g;
    const int l  = t % 3;
    const int ei = t / 3;
    const float e = energy[ei], negE = -e;
    const float ll1 = (float)(l * (l + 1));
    // uniform: seg s covers j = jstart .. jstart+27 (s31: last 2 are dummies)
    const int jstart = 5 + 28 * s;

    const float4* gq = (const float4*)(&gtp[jstart + 3]);   // group G = j jstart+4G..+3
    float ff0, ff1, ff2, ff3;
    {
        const float4 wF = *(const float4*)(&gtp[jstart - 1]);  // j-4..j-1
        ff0 = fmaf(wF.x, fmaf(ll1, wF.x, -1.0f), negE);
        ff1 = fmaf(wF.y, fmaf(ll1, wF.y, -1.0f), negE);
        ff2 = fmaf(wF.z, fmaf(ll1, wF.z, -1.0f), negE);
        ff3 = fmaf(wF.w, fmaf(ll1, wF.w, -1.0f), negE);
    }
    float F0 = ff0, F1 = ff1, F2 = ff2, F3 = ff3;

    float ca, cb, cc_, cd;
#define COEF(RI, FA,FB,FC,FD) \
    { float f4 = fmaf(RI, fmaf(ll1, RI, -1.0f), negE); \
      float x  = kC * f4; \
      float iv = fmaf(x, x, x) + 1.0f; \
      ca  = fmaf(kC  * FA, iv, -1.0f); \
      cb  = fmaf(kK1 * FB, iv,  2.0f); \
      cc_ = fmaf(kK2 * FC, iv, -2.0f); \
      cd  = fmaf(kK1 * FD, iv,  2.0f); \
      FA = f4; }

#define MSTEP(RI, FA,FB,FC,FD, RA,RB,RC,RD) \
    { COEF(RI, FA,FB,FC,FD) \
      RA[0] = fmaf(cd,RD[0], fmaf(cc_,RC[0], fmaf(cb,RB[0], ca*RA[0]))); \
      RA[1] = fmaf(cd,RD[1], fmaf(cc_,RC[1], fmaf(cb,RB[1], ca*RA[1]))); \
      RA[2] = fmaf(cd,RD[2], fmaf(cc_,RC[2], fmaf(cb,RB[2], ca*RA[2]))); \
      RA[3] = fmaf(cd,RD[3], fmaf(cc_,RC[3], fmaf(cb,RB[3], ca*RA[3]))); }

    // ---- phase 1: companion products, uniform 28 steps for s<=30 ----
    if (s != 31) {
        float ra[4] = {1,0,0,0}, rb[4] = {0,1,0,0}, rc[4] = {0,0,1,0}, rd[4] = {0,0,0,1};
        #pragma unroll
        for (int gi = 0; gi < 7; ++gi) {
            const float4 w = gq[gi];
            MSTEP(w.x, F0,F1,F2,F3, ra,rb,rc,rd)
            MSTEP(w.y, F1,F2,F3,F0, rb,rc,rd,ra)
            MSTEP(w.z, F2,F3,F0,F1, rc,rd,ra,rb)
            MSTEP(w.w, F3,F0,F1,F2, rd,ra,rb,rc)
        }
        *(float4*)&sM[s][0][g][0] = make_float4(ra[0], ra[1], ra[2], ra[3]);
        *(float4*)&sM[s][1][g][0] = make_float4(rb[0], rb[1], rb[2], rb[3]);
        *(float4*)&sM[s][2][g][0] = make_float4(rc[0], rc[1], rc[2], rc[3]);
        *(float4*)&sM[s][3][g][0] = make_float4(rd[0], rd[1], rd[2], rd[3]);
    }
    __syncthreads();

    // ---- phase 2: per-chain serial combine (lanes tid 0..15). Reads each
    // segment's matrix rows, then overwrites row 0 with that segment's start
    // state (read-before-write makes the alias safe).
    if (s == 0) {
        const float se  = sqrtf(fabsf(e));
        const float rfc = (l == 0) ? 1.0f : ((l == 1) ? (1.0f/3.0f) : (1.0f/15.0f));
        const float rt1 = (l == 0) ? (1.0f/3.0f) : ((l == 1) ? (1.0f/5.0f) : (1.0f/7.0f));
        const float rt2 = (l == 0) ? (1.0f/30.0f) : ((l == 1) ? (1.0f/70.0f) : (1.0f/126.0f));
        float pw[5];
        #pragma unroll
        for (int k = 0; k < 5; ++k) {
            float rinf = 99.6f + 0.1f * (float)k;
            float x  = rinf * se;
            float xl = (l == 0) ? 1.0f : ((l == 1) ? x : x * x);
            float h  = x * x * 0.5f;
            pw[k] = rinf * (xl * rfc * (1.0f + h * rt1 + (h * h) * rt2));
        }
        uinf[(size_t)899 * kNCH + t] = pw[4];
        float st0 = pw[1], st1 = pw[2], st2 = pw[3], st3 = pw[4];
        for (int ss = 0; ss < kSeg; ++ss) {
            if (ss < kSeg - 1) {
                float4 M0 = *(const float4*)&sM[ss][0][g][0];
                float4 M1 = *(const float4*)&sM[ss][1][g][0];
                float4 M2 = *(const float4*)&sM[ss][2][g][0];
                float4 M3 = *(const float4*)&sM[ss][3][g][0];
                *(float4*)&sM[ss][0][g][0] = make_float4(st0, st1, st2, st3);
                float n0 = fmaf(M0.w,st3, fmaf(M0.z,st2, fmaf(M0.y,st1, M0.x*st0)));
                float n1 = fmaf(M1.w,st3, fmaf(M1.z,st2, fmaf(M1.y,st1, M1.x*st0)));
                float n2 = fmaf(M2.w,st3, fmaf(M2.z,st2, fmaf(M2.y,st1, M2.x*st0)));
                float n3 = fmaf(M3.w,st3, fmaf(M3.z,st2, fmaf(M3.y,st1, M3.x*st0)));
                st0 = n0; st1 = n1; st2 = n2; st3 = n3;
            } else {
                *(float4*)&sM[ss][0][g][0] = make_float4(st0, st1, st2, st3);
            }
        }
    }
    __syncthreads();

    // ---- phase 3: uniform 28-step replay (s31: last 2 steps dummy) ----
    // slot K=0..3 <-> j === 1,2,3,0 mod 4 <-> row === 2,1,0,3 mod 4:
    // weights {acc2, 32*u^4, 14*u^4, 32*u^4}.
    float W0[4] = {0.0f, 32.0f, 14.0f, 32.0f};
    float V0[4] = {1.0f, 0.0f, 0.0f, 0.0f};
    float WR[4] = {0.0f, 32.0f, 14.0f, 32.0f};
    float VR[4] = {1.0f, 0.0f, 0.0f, 0.0f};
    if (s == 0) {   // rows 898,897 beyond integration; j=7 -> terminal boundary 7
        W0[0]=0.0f; V0[0]=0.0f; W0[1]=0.0f; W0[2]=7.0f; W0[3]=32.0f;
    }

    F0 = ff0; F1 = ff1; F2 = ff2; F3 = ff3;
    float p0, p1, p2, p3;
    {
        float4 P = *(const float4*)&sM[s][0][g][0];
        p0 = P.x; p1 = P.y; p2 = P.z; p3 = P.w;
    }
    float acc4 = 0.0f, acc2 = 0.0f;
    float* ptr = uinf + (size_t)(903 - jstart) * kNCH + t;
#define RSTEPW(RI, FA,FB,FC,FD, PA,PB,PC,PD, W,V,K) \
    { COEF(RI, FA,FB,FC,FD) \
      float nw = fmaf(cd,PD, fmaf(cc_,PC, fmaf(cb,PB, ca*PA))); \
      PA = nw; *ptr = nw; ptr -= kNCH; \
      float v2 = nw*nw, v4 = v2*v2; \
      acc4 = fmaf(W[K], v4, acc4); \
      acc2 = fmaf(V[K], v2, acc2); }
#define PG(G, W, V) \
    { const float4 w = gq[G]; \
      RSTEPW(w.x, F0,F1,F2,F3, p0,p1,p2,p3, W,V,0) \
      RSTEPW(w.y, F1,F2,F3,F0, p1,p2,p3,p0, W,V,1) \
      RSTEPW(w.z, F2,F3,F0,F1, p2,p3,p0,p1, W,V,2) \
      RSTEPW(w.w, F3,F0,F1,F2, p3,p0,p1,p2, W,V,3) }

    PG(0, W0, V0)
    PG(1, WR, VR) PG(2, WR, VR) PG(3, WR, VR) PG(4, WR, VR) PG(5, WR, VR)
    // after 6 groups rotation is restored: p0..p3 = w[jstart+20 .. jstart+23]
    // s31 (jstart=873): p1,p2,p3 = w894,w895,w896
    float h0 = p1, h1 = p2, h2 = p3;
    if (s == 31) { WR[2] = 0.0f; WR[3] = 0.0f; }   // j=899,900 dummies: weight 0
    PG(6, WR, VR)
    // s31: p0,p1 = w897,w898 (dummy steps landed in p2,p3; their stores to
    // rows 4,3 are overwritten by the epilogue below in the same thread)
    float h3 = p0, h4 = p1;
#undef PG
#undef RSTEPW

    {   // per-segment integral partials -> row-1 slots (matrices are dead)
        float2 rr; rr.x = acc4; rr.y = acc2;
        *(float2*)&sF[s * 256 + 64 + 4 * g] = rr;
    }
    __syncthreads();

    if (s == kSeg - 1) {
        float a4 = 0.0f, a2 = 0.0f;
        #pragma unroll
        for (int ss = 0; ss < kSeg; ++ss) {
            float2 rr = *(const float2*)&sF[ss * 256 + 64 + 4 * g];
            a4 += rr.x; a2 += rr.y;
        }
        // h0..h4 = w894..w898 -> u_infty rows 0..4 (state vector copy)
        uinf[(size_t)0 * kNCH + t] = h0;
        uinf[(size_t)1 * kNCH + t] = h1;
        uinf[(size_t)2 * kNCH + t] = h2;
        uinf[(size_t)3 * kNCH + t] = h3;
        uinf[(size_t)4 * kNCH + t] = h4;
        float q0 = h0*h0, q1 = h1*h1, q2 = h2*h2, q3 = h3*h3, q4 = h4*h4;
        a4 += 7.0f*q0*q0 + 32.0f*q1*q1 + 32.0f*q3*q3 + 14.0f*q4*q4;
        a2 += q2;
        float integ = fmaf(12.0f, a2, a4) * (2.0f * 0.1f / 45.0f);
        float deriv = fmaf(25.0f, h0, fmaf(-48.0f, h1, fmaf(36.0f, h2,
                      fmaf(-16.0f, h3, 3.0f * h4)))) * (1.0f / 1.2f);
        ws[t]        = deriv / h0;            // lfunc_out (pre energy-reversal)
        ws[kNCH + t] = integ / (h0 * h0);     // integ_out / u_infty[0]^2
    }
#undef MSTEP
#undef COEF
}

__global__ __launch_bounds__(256) void final_kernel(const float* __restrict__ energy,
                                                    const float* __restrict__ ws,
                                                    float* __restrict__ out)
{
    int t = (int)blockIdx.x * 256 + (int)threadIdx.x;
    if (t >= kNCH) return;
    int l = t % 3, ei = t / 3;
    float lf_out = ws[(kNE - 1 - ei) * 3 + l];   // energy-axis reversed
    float lf_in  = ws[2 * kNCH + t];
    float den    = ws[kNCH + t] + ws[3 * kNCH + t];
    out[t] = energy[ei] - (lf_out - lf_in) / den;
}

extern "C" void kernel_launch(void* const* d_in, const int* in_sizes, int n_in,
                              void* d_out, int out_size, void* d_ws, size_t ws_size,
                              hipStream_t stream) {
    (void)in_sizes; (void)n_in; (void)out_size; (void)ws_size;
    const float* energy = (const float*)d_in[0];
    float* out = (float*)d_out;
    float* ws  = (float*)d_ws;   // 4*12288 floats = 192 KB scratch
    // MEASUREMENT: 3x identical solve launches (idempotent). True solve
    // duration = (dur_r11 - dur_r10) / 2, fill-row-normalized.
    solve_kernel<<<kZeroBlocks + kInfBlocks, 512, 0, stream>>>(energy, out, ws);
    solve_kernel<<<kZeroBlocks + kInfBlocks, 512, 0, stream>>>(energy, out, ws);
    solve_kernel<<<kZeroBlocks + kInfBlocks, 512, 0, stream>>>(energy, out, ws);
    final_kernel<<<kNCH / 256, 256, 0, stream>>>(energy, ws, out);
}

// Round 5
// 84.906 us; speedup vs baseline: 1.5097x; 1.5097x over previous
//
#include <hip/hip_runtime.h>

// EvalEig round 12: r11 measurement decomposed dur exactly: fill(44, harness
// poison, fixed) + solve_inpath(38.8) + final(3). Steady-state solve = 21.2us
// (2nd/3rd launches), so the first-after-fill launch carries an ~18us penalty
// with NO saturated counter (VALU 27%, HBM 13%, occ 55%) -> memory-system
// interaction with the 256MiB resident/dirty poison: our 48MB of partial-line
// output stores allocate L2/L3 lines against it. This round: all stores to
// `out` are __builtin_nontemporal_store (no cache allocation, no contention);
// ws stores stay normal (re-read by final_kernel). Single solve launch.
// Predict dur 85.8 -> ~68-72 if theory right; ~85 if null -> pivot to
// steady-state ILP and accept fill as floor.

namespace {
constexpr int kNE    = 4096;
constexpr int kNCH   = kNE * 3;        // 12288 chains
constexpr int kMatch = 100;
constexpr float kC   = 3.0f / 40.0f * 0.01f;
constexpr float kK1  = 13.0f / 15.0f * 0.01f;
constexpr float kK2  = 7.0f / 60.0f * 0.01f;
constexpr int kSeg        = 32;           // segments per chain
constexpr int kCPB        = 16;           // chains per block
constexpr int kZeroBlocks = kNCH / 512;   // 24
constexpr int kInfBlocks  = kNCH / kCPB;  // 768
}

__device__ __forceinline__ float rcp_f(float x) { return __builtin_amdgcn_rcpf(x); }
__device__ __forceinline__ float rcp_nr(float x) {
    float r = __builtin_amdgcn_rcpf(x);
    return fmaf(fmaf(-x, r, 1.0f), r, r);
}
__device__ __forceinline__ void nt_store(float* p, float v) {
    __builtin_nontemporal_store(v, p);
}

__global__ __launch_bounds__(512, 4) void solve_kernel(const float* __restrict__ energy,
                                                       float* __restrict__ out,
                                                       float* __restrict__ ws)
{
    // gtp[k] = 1/(100 - 0.1*(k-3)) for k in [4,901] (j = k-3 in [1,898]);
    // dummies = 1.0 elsewhere. +3 shift makes every group read 16B-aligned
    // (jstart === 1 mod 4  ->  padded base jstart+3 === 0 mod 4).
    __shared__ __align__(16) float gtp[908];  // 3.6 KB
    __shared__ float sM[kSeg][4][kCPB][4];    // 32 KB: [seg][matrix row][chain][col]
    float* sF = &sM[0][0][0][0];

    const int bid = (int)blockIdx.x;
    const int tid = (int)threadIdx.x;
    float* uzero = out + kNCH;
    float* uinf  = out + kNCH + (size_t)kMatch * kNCH;

    if (bid < kZeroBlocks) {
        // ---------------- u_zero: outward solve, 94 steps, 1 thread/chain ----
        const int t  = bid * 512 + tid;
        const int l  = t % 3;
        const int ei = t / 3;
        const float e = energy[ei], negE = -e;
        const float ll1 = (float)(l * (l + 1));
        const float rdiv = (l == 0) ? 0.5f : ((l == 1) ? 0.25f : (1.0f/6.0f));
        float p0,p1,p2,p3,p4;
        {
            float pw[5];
            #pragma unroll
            for (int k = 0; k < 5; ++k) {
                float r = 0.1f * (float)(k + 1);
                float rl1 = (l == 0) ? r : ((l == 1) ? r*r : r*r*r);
                pw[k] = rl1 - (rl1 * r) * rdiv;
                nt_store(&uzero[(size_t)k * kNCH + t], pw[k]);
            }
            nt_store(&uzero[(size_t)5 * kNCH + t], pw[4]);
            p0=pw[0]; p1=pw[1]; p2=pw[2]; p3=pw[3]; p4=pw[4];
        }
        float acc4, acc2;
        {
            float q0=p0*p0, q1=p1*p1, q2=p2*p2, q3=p3*p3, q4=p4*p4;
            acc4 = 7.0f*q0*q0 + 32.0f*q1*q1 + 32.0f*q3*q3 + 14.0f*q4*q4 + 32.0f*q4*q4;
            acc2 = q2;
        }
        float f0, f1, f2, f3;
        {
            float i1 = rcp_f(0.2f), i2 = rcp_f(0.3f), i3 = rcp_f(0.4f), i4 = rcp_f(0.5f);
            f0 = fmaf(i1, fmaf(ll1, i1, -1.0f), negE);
            f1 = fmaf(i2, fmaf(ll1, i2, -1.0f), negE);
            f2 = fmaf(i3, fmaf(ll1, i3, -1.0f), negE);
            f3 = fmaf(i4, fmaf(ll1, i4, -1.0f), negE);
        }
        float* ptr = uzero + (size_t)6 * kNCH + t;
        #pragma unroll 4
        for (int j = 5; j <= 98; ++j) {
            float ri = rcp_f(fmaf((float)j, 0.1f, 0.1f));
            float f4 = fmaf(ri, fmaf(ll1, ri, -1.0f), negE);
            float iv = rcp_f(fmaf(-kC, f4, 1.0f));
            float a  = fmaf(kC  * f0, iv, -1.0f);
            float b  = fmaf(kK1 * f1, iv,  2.0f);
            float cc = fmaf(kK2 * f2, iv, -2.0f);
            float d  = fmaf(kK1 * f3, iv,  2.0f);
            float nw = fmaf(d, p4, fmaf(cc, p3, fmaf(b, p2, a * p1)));
            nt_store(ptr, nw); ptr += kNCH;
            float v2 = nw*nw, v4 = v2*v2;
            if (j <= 94) {
                int m = (j + 1) & 3;
                if (m == 2)      acc2 += v2;
                else if (m == 0) acc4 += 14.0f * v4;
                else             acc4 += 32.0f * v4;
            } else if (j == 95) {
                acc4 += 7.0f * v4;
            }
            f0 = f1; f1 = f2; f2 = f3; f3 = f4;
            p0 = p1; p1 = p2; p2 = p3; p3 = p4; p4 = nw;
        }
        float integ = fmaf(12.0f, acc2, acc4) * (2.0f * 0.1f / 45.0f);
        float deriv = fmaf(25.0f, p4, fmaf(-48.0f, p3, fmaf(36.0f, p2,
                      fmaf(-16.0f, p1, 3.0f * p0)))) * (1.0f / 1.2f);
        ws[2 * kNCH + t] = deriv / p4;
        ws[3 * kNCH + t] = integ / (p4 * p4);
        return;
    }

    // ---------------- u_infty: 32-segment inward solve ----------------
    for (int k = tid; k < 908; k += 512) {
        int j = k - 3;
        gtp[k] = (j >= 1 && j <= 898) ? rcp_nr(fmaf((float)j, -0.1f, 100.0f)) : 1.0f;
    }
    __syncthreads();

    const int b = bid - kZeroBlocks;
    const int g = tid & (kCPB - 1);        // chain within block
    const int s = tid >> 4;                // segment 0..31 (4 per wave)
    const int t = b * kCPB + g;
    const int l  = t % 3;
    const int ei = t / 3;
    const float e = energy[ei], negE = -e;
    const float ll1 = (float)(l * (l + 1));
    // uniform: seg s covers j = jstart .. jstart+27 (s31: last 2 are dummies)
    const int jstart = 5 + 28 * s;

    const float4* gq = (const float4*)(&gtp[jstart + 3]);   // group G = j jstart+4G..+3
    float ff0, ff1, ff2, ff3;
    {
        const float4 wF = *(const float4*)(&gtp[jstart - 1]);  // j-4..j-1
        ff0 = fmaf(wF.x, fmaf(ll1, wF.x, -1.0f), negE);
        ff1 = fmaf(wF.y, fmaf(ll1, wF.y, -1.0f), negE);
        ff2 = fmaf(wF.z, fmaf(ll1, wF.z, -1.0f), negE);
        ff3 = fmaf(wF.w, fmaf(ll1, wF.w, -1.0f), negE);
    }
    float F0 = ff0, F1 = ff1, F2 = ff2, F3 = ff3;

    float ca, cb, cc_, cd;
#define COEF(RI, FA,FB,FC,FD) \
    { float f4 = fmaf(RI, fmaf(ll1, RI, -1.0f), negE); \
      float x  = kC * f4; \
      float iv = fmaf(x, x, x) + 1.0f; \
      ca  = fmaf(kC  * FA, iv, -1.0f); \
      cb  = fmaf(kK1 * FB, iv,  2.0f); \
      cc_ = fmaf(kK2 * FC, iv, -2.0f); \
      cd  = fmaf(kK1 * FD, iv,  2.0f); \
      FA = f4; }

#define MSTEP(RI, FA,FB,FC,FD, RA,RB,RC,RD) \
    { COEF(RI, FA,FB,FC,FD) \
      RA[0] = fmaf(cd,RD[0], fmaf(cc_,RC[0], fmaf(cb,RB[0], ca*RA[0]))); \
      RA[1] = fmaf(cd,RD[1], fmaf(cc_,RC[1], fmaf(cb,RB[1], ca*RA[1]))); \
      RA[2] = fmaf(cd,RD[2], fmaf(cc_,RC[2], fmaf(cb,RB[2], ca*RA[2]))); \
      RA[3] = fmaf(cd,RD[3], fmaf(cc_,RC[3], fmaf(cb,RB[3], ca*RA[3]))); }

    // ---- phase 1: companion products, uniform 28 steps for s<=30 ----
    if (s != 31) {
        float ra[4] = {1,0,0,0}, rb[4] = {0,1,0,0}, rc[4] = {0,0,1,0}, rd[4] = {0,0,0,1};
        #pragma unroll
        for (int gi = 0; gi < 7; ++gi) {
            const float4 w = gq[gi];
            MSTEP(w.x, F0,F1,F2,F3, ra,rb,rc,rd)
            MSTEP(w.y, F1,F2,F3,F0, rb,rc,rd,ra)
            MSTEP(w.z, F2,F3,F0,F1, rc,rd,ra,rb)
            MSTEP(w.w, F3,F0,F1,F2, rd,ra,rb,rc)
        }
        *(float4*)&sM[s][0][g][0] = make_float4(ra[0], ra[1], ra[2], ra[3]);
        *(float4*)&sM[s][1][g][0] = make_float4(rb[0], rb[1], rb[2], rb[3]);
        *(float4*)&sM[s][2][g][0] = make_float4(rc[0], rc[1], rc[2], rc[3]);
        *(float4*)&sM[s][3][g][0] = make_float4(rd[0], rd[1], rd[2], rd[3]);
    }
    __syncthreads();

    // ---- phase 2: per-chain serial combine (lanes tid 0..15). Reads each
    // segment's matrix rows, then overwrites row 0 with that segment's start
    // state (read-before-write makes the alias safe).
    if (s == 0) {
        const float se  = sqrtf(fabsf(e));
        const float rfc = (l == 0) ? 1.0f : ((l == 1) ? (1.0f/3.0f) : (1.0f/15.0f));
        const float rt1 = (l == 0) ? (1.0f/3.0f) : ((l == 1) ? (1.0f/5.0f) : (1.0f/7.0f));
        const float rt2 = (l == 0) ? (1.0f/30.0f) : ((l == 1) ? (1.0f/70.0f) : (1.0f/126.0f));
        float pw[5];
        #pragma unroll
        for (int k = 0; k < 5; ++k) {
            float rinf = 99.6f + 0.1f * (float)k;
            float x  = rinf * se;
            float xl = (l == 0) ? 1.0f : ((l == 1) ? x : x * x);
            float h  = x * x * 0.5f;
            pw[k] = rinf * (xl * rfc * (1.0f + h * rt1 + (h * h) * rt2));
        }
        nt_store(&uinf[(size_t)899 * kNCH + t], pw[4]);
        float st0 = pw[1], st1 = pw[2], st2 = pw[3], st3 = pw[4];
        for (int ss = 0; ss < kSeg; ++ss) {
            if (ss < kSeg - 1) {
                float4 M0 = *(const float4*)&sM[ss][0][g][0];
                float4 M1 = *(const float4*)&sM[ss][1][g][0];
                float4 M2 = *(const float4*)&sM[ss][2][g][0];
                float4 M3 = *(const float4*)&sM[ss][3][g][0];
                *(float4*)&sM[ss][0][g][0] = make_float4(st0, st1, st2, st3);
                float n0 = fmaf(M0.w,st3, fmaf(M0.z,st2, fmaf(M0.y,st1, M0.x*st0)));
                float n1 = fmaf(M1.w,st3, fmaf(M1.z,st2, fmaf(M1.y,st1, M1.x*st0)));
                float n2 = fmaf(M2.w,st3, fmaf(M2.z,st2, fmaf(M2.y,st1, M2.x*st0)));
                float n3 = fmaf(M3.w,st3, fmaf(M3.z,st2, fmaf(M3.y,st1, M3.x*st0)));
                st0 = n0; st1 = n1; st2 = n2; st3 = n3;
            } else {
                *(float4*)&sM[ss][0][g][0] = make_float4(st0, st1, st2, st3);
            }
        }
    }
    __syncthreads();

    // ---- phase 3: uniform 28-step replay (s31: last 2 steps dummy) ----
    // slot K=0..3 <-> j === 1,2,3,0 mod 4 <-> row === 2,1,0,3 mod 4:
    // weights {acc2, 32*u^4, 14*u^4, 32*u^4}.
    float W0[4] = {0.0f, 32.0f, 14.0f, 32.0f};
    float V0[4] = {1.0f, 0.0f, 0.0f, 0.0f};
    float WR[4] = {0.0f, 32.0f, 14.0f, 32.0f};
    float VR[4] = {1.0f, 0.0f, 0.0f, 0.0f};
    if (s == 0) {   // rows 898,897 beyond integration; j=7 -> terminal boundary 7
        W0[0]=0.0f; V0[0]=0.0f; W0[1]=0.0f; W0[2]=7.0f; W0[3]=32.0f;
    }

    F0 = ff0; F1 = ff1; F2 = ff2; F3 = ff3;
    float p0, p1, p2, p3;
    {
        float4 P = *(const float4*)&sM[s][0][g][0];
        p0 = P.x; p1 = P.y; p2 = P.z; p3 = P.w;
    }
    float acc4 = 0.0f, acc2 = 0.0f;
    float* ptr = uinf + (size_t)(903 - jstart) * kNCH + t;
#define RSTEPW(RI, FA,FB,FC,FD, PA,PB,PC,PD, W,V,K) \
    { COEF(RI, FA,FB,FC,FD) \
      float nw = fmaf(cd,PD, fmaf(cc_,PC, fmaf(cb,PB, ca*PA))); \
      PA = nw; nt_store(ptr, nw); ptr -= kNCH; \
      float v2 = nw*nw, v4 = v2*v2; \
      acc4 = fmaf(W[K], v4, acc4); \
      acc2 = fmaf(V[K], v2, acc2); }
#define PG(G, W, V) \
    { const float4 w = gq[G]; \
      RSTEPW(w.x, F0,F1,F2,F3, p0,p1,p2,p3, W,V,0) \
      RSTEPW(w.y, F1,F2,F3,F0, p1,p2,p3,p0, W,V,1) \
      RSTEPW(w.z, F2,F3,F0,F1, p2,p3,p0,p1, W,V,2) \
      RSTEPW(w.w, F3,F0,F1,F2, p3,p0,p1,p2, W,V,3) }

    PG(0, W0, V0)
    PG(1, WR, VR) PG(2, WR, VR) PG(3, WR, VR) PG(4, WR, VR) PG(5, WR, VR)
    // after 6 groups rotation is restored: p0..p3 = w[jstart+20 .. jstart+23]
    // s31 (jstart=873): p1,p2,p3 = w894,w895,w896
    float h0 = p1, h1 = p2, h2 = p3;
    if (s == 31) { WR[2] = 0.0f; WR[3] = 0.0f; }   // j=899,900 dummies: weight 0
    PG(6, WR, VR)
    // s31: p0,p1 = w897,w898 (dummy steps landed in p2,p3; their stores to
    // rows 4,3 are overwritten by the epilogue below in the same thread)
    float h3 = p0, h4 = p1;
#undef PG
#undef RSTEPW

    {   // per-segment integral partials -> row-1 slots (matrices are dead)
        float2 rr; rr.x = acc4; rr.y = acc2;
        *(float2*)&sF[s * 256 + 64 + 4 * g] = rr;
    }
    __syncthreads();

    if (s == kSeg - 1) {
        float a4 = 0.0f, a2 = 0.0f;
        #pragma unroll
        for (int ss = 0; ss < kSeg; ++ss) {
            float2 rr = *(const float2*)&sF[ss * 256 + 64 + 4 * g];
            a4 += rr.x; a2 += rr.y;
        }
        // h0..h4 = w894..w898 -> u_infty rows 0..4 (state vector copy)
        nt_store(&uinf[(size_t)0 * kNCH + t], h0);
        nt_store(&uinf[(size_t)1 * kNCH + t], h1);
        nt_store(&uinf[(size_t)2 * kNCH + t], h2);
        nt_store(&uinf[(size_t)3 * kNCH + t], h3);
        nt_store(&uinf[(size_t)4 * kNCH + t], h4);
        float q0 = h0*h0, q1 = h1*h1, q2 = h2*h2, q3 = h3*h3, q4 = h4*h4;
        a4 += 7.0f*q0*q0 + 32.0f*q1*q1 + 32.0f*q3*q3 + 14.0f*q4*q4;
        a2 += q2;
        float integ = fmaf(12.0f, a2, a4) * (2.0f * 0.1f / 45.0f);
        float deriv = fmaf(25.0f, h0, fmaf(-48.0f, h1, fmaf(36.0f, h2,
                      fmaf(-16.0f, h3, 3.0f * h4)))) * (1.0f / 1.2f);
        ws[t]        = deriv / h0;            // lfunc_out (pre energy-reversal)
        ws[kNCH + t] = integ / (h0 * h0);     // integ_out / u_infty[0]^2
    }
#undef MSTEP
#undef COEF
}

__global__ __launch_bounds__(256) void final_kernel(const float* __restrict__ energy,
                                                    const float* __restrict__ ws,
                                                    float* __restrict__ out)
{
    int t = (int)blockIdx.x * 256 + (int)threadIdx.x;
    if (t >= kNCH) return;
    int l = t % 3, ei = t / 3;
    float lf_out = ws[(kNE - 1 - ei) * 3 + l];   // energy-axis reversed
    float lf_in  = ws[2 * kNCH + t];
    float den    = ws[kNCH + t] + ws[3 * kNCH + t];
    nt_store(&out[t], energy[ei] - (lf_out - lf_in) / den);
}

extern "C" void kernel_launch(void* const* d_in, const int* in_sizes, int n_in,
                              void* d_out, int out_size, void* d_ws, size_t ws_size,
                              hipStream_t stream) {
    (void)in_sizes; (void)n_in; (void)out_size; (void)ws_size;
    const float* energy = (const float*)d_in[0];
    float* out = (float*)d_out;
    float* ws  = (float*)d_ws;   // 4*12288 floats = 192 KB scratch
    solve_kernel<<<kZeroBlocks + kInfBlocks, 512, 0, stream>>>(energy, out, ws);
    final_kernel<<<kNCH / 256, 256, 0, stream>>>(energy, ws, out);
}